// Round 6
// baseline (94.364 us; speedup 1.0000x reference)
//
#include <hip/hip_runtime.h>
#include <hip/hip_bf16.h>
#include <stdint.h>

// SimCLR loss, n=8192, d=128, T=0.07.
// R6: exploit sim-matrix SYMMETRY — only triangle block-tiles computed; each
// off-diagonal tile's exp values are reduced two ways (over cols -> E[rows],
// over rows -> E[cols]), halving MFMA work (1.05M -> 540K instrs) and exp
// count. Matrix-pipe floor 4.3us (per-SIMD 16x16x32 = ~19.4cy). B-tile regs
// double-buffered (static-indexed, full unroll) for load/compute overlap.
//  k_normalize: fp32 -> row-L2-normalized bf16 fn; zeroes out[0]
//  k_simexp:    triangle tiles; E[i] += sum_j exp2((dot_ij-1)*s) via atomicAdd
//  k_finalize:  term = 1/T + ln(E[i] - exp2((sd-1)*s)) - pd/T; mean via atomic

#define N_ROWS 8192
#define DIM    128
#define HALF_N 4096
#define NBR    64            // 8192 / 128-row band
#define BROWS  128           // rows per block (4 waves x 32)
#define WROWS  32            // rows per wave
#define NJ     8             // 16-col tiles per 128-col slice
#define NTRI   (NBR * (NBR + 1) / 2)   // 2080 triangle blocks

static constexpr float INV_T = 14.285714285714286f;   // 1/0.07
static constexpr float SCALE = 20.60992915555662f;    // log2(e)/0.07

typedef __attribute__((ext_vector_type(8))) short short8;   // 8 bf16 = 4 VGPR
typedef __attribute__((ext_vector_type(4))) float f32x4;

#if __has_builtin(__builtin_amdgcn_exp2f)
__device__ inline float fast_exp2(float x) { return __builtin_amdgcn_exp2f(x); }
#else
__device__ inline float fast_exp2(float x) { return exp2f(x); }
#endif

__device__ inline float bf_lo(uint32_t u) { return __uint_as_float(u << 16); }
__device__ inline float bf_hi(uint32_t u) { return __uint_as_float(u & 0xFFFF0000u); }
__device__ inline uint16_t f2bf(float x) {
    uint32_t u = __float_as_uint(x);
    return (uint16_t)((u + 0x7FFFu + ((u >> 16) & 1u)) >> 16);   // RNE
}

// ---------------- kernel 1: row L2-normalize, fp32 -> bf16 ----------------
__global__ __launch_bounds__(256) void k_normalize(const float* __restrict__ f,
                                                   uint16_t* __restrict__ fn,
                                                   float* __restrict__ out) {
    if (blockIdx.x == 0 && threadIdx.x == 0) out[0] = 0.0f;   // init for atomics
    int wid  = (blockIdx.x * blockDim.x + threadIdx.x) >> 6;   // one wave per row
    int lane = threadIdx.x & 63;
    const float2* src = (const float2*)(f + (size_t)wid * DIM);
    float2 v = src[lane];
    float ss = v.x * v.x + v.y * v.y;
    #pragma unroll
    for (int m = 1; m < 64; m <<= 1) ss += __shfl_xor(ss, m, 64);
    float inv = rsqrtf(ss);
    ushort2 o;
    o.x = f2bf(v.x * inv);
    o.y = f2bf(v.y * inv);
    ((ushort2*)(fn + (size_t)wid * DIM))[lane] = o;
}

// ---------------- kernel 2: triangle sim + exp-sum (MFMA) ----------------
// 1D grid of NTRI blocks -> (bx, by) with by >= bx over 64x64 band space.
// Block = 4 waves x 32 rows = 128 rows (band bx), 128 cols (band by).
// Off-diag tiles: exp values feed E[rows] (reduce over lr) AND E[cols]
// (reduce over lk,r). Diag tiles: rows only (self term removed in finalize).
__global__ __launch_bounds__(256) void k_simexp(const uint16_t* __restrict__ fn,
                                                float* __restrict__ E) {
    // decode triangular block index (uniform scalar loop)
    int bx = 0, rem = blockIdx.x;
    while (rem >= NBR - bx) { rem -= NBR - bx; ++bx; }
    const int by = bx + rem;
    const bool diag = (by == bx);

    const int lane = threadIdx.x & 63;
    const int w    = threadIdx.x >> 6;
    const int lr = lane & 15;
    const int lk = lane >> 4;
    const int ib = bx * BROWS + w * WROWS;
    const int jb = by * BROWS;

    const short8* fn8 = (const short8*)fn;

    // A fragments: row ib+mt*16+lr, dims kc*32+lk*8..+8  (32 VGPRs)
    short8 Af[2][4];
    #pragma unroll
    for (int mt = 0; mt < 2; ++mt)
        #pragma unroll
        for (int kc = 0; kc < 4; ++kc)
            Af[mt][kc] = fn8[(size_t)(ib + mt * 16 + lr) * 16 + kc * 4 + lk];

    float es[2][4];
    #pragma unroll
    for (int mt = 0; mt < 2; ++mt)
        #pragma unroll
        for (int r = 0; r < 4; ++r) es[mt][r] = 0.0f;

    // B row for tile jt: jb + jt*16 + lr  -> fn8 offset (jb+jt*16+lr)*16 + kc*4+lk
    const short8* bbase = fn8 + ((size_t)jb + lr) * 16 + lk;

    short8 Bn[2][4];                       // register double-buffer (static idx)
    #pragma unroll
    for (int kc = 0; kc < 4; ++kc) Bn[0][kc] = bbase[kc * 4];

    #pragma unroll
    for (int jt = 0; jt < NJ; ++jt) {
        if (jt + 1 < NJ) {
            const short8* nb = bbase + (size_t)(jt + 1) * 256;
            #pragma unroll
            for (int kc = 0; kc < 4; ++kc) Bn[(jt + 1) & 1][kc] = nb[kc * 4];
        }
        float cs = 0.0f;
        #pragma unroll
        for (int mt = 0; mt < 2; ++mt) {
            f32x4 acc = {0.0f, 0.0f, 0.0f, 0.0f};
            #pragma unroll
            for (int kc = 0; kc < 4; ++kc)
                acc = __builtin_amdgcn_mfma_f32_16x16x32_bf16(Af[mt][kc], Bn[jt & 1][kc], acc, 0, 0, 0);
            #pragma unroll
            for (int r = 0; r < 4; ++r) {
                float e = fast_exp2(fmaf(acc[r], SCALE, -SCALE));
                es[mt][r] += e;           // row-sum accumulator
                cs += e;                  // col partial for this tile
            }
        }
        if (!diag) {
            // col j = jb + jt*16 + lr; sum over rows = over (lk, r[, mt])
            cs += __shfl_xor(cs, 16, 64);
            cs += __shfl_xor(cs, 32, 64);
            if (lk == 0)
                atomicAdd(&E[jb + jt * 16 + lr], cs);
        }
    }

    // row sums: D col = lr; reduce over 16 col-lanes. row = lk*4 + r.
    #pragma unroll
    for (int mt = 0; mt < 2; ++mt)
        #pragma unroll
        for (int r = 0; r < 4; ++r) {
            float v = es[mt][r];
            v += __shfl_xor(v, 1, 64);
            v += __shfl_xor(v, 2, 64);
            v += __shfl_xor(v, 4, 64);
            v += __shfl_xor(v, 8, 64);
            if (lr == 0)
                atomicAdd(&E[ib + mt * 16 + lk * 4 + r], v);
        }
}

// ---------------- kernel 3: finalize + mean (atomic) ----------------
__global__ __launch_bounds__(256) void k_finalize(const uint16_t* __restrict__ fn,
                                                  const float* __restrict__ E,
                                                  float* __restrict__ out) {
    __shared__ float sm[4];
    int wid  = (blockIdx.x * blockDim.x + threadIdx.x) >> 6;   // one wave per row
    int lane = threadIdx.x & 63;
    int partner = (wid + HALF_N) & (N_ROWS - 1);
    const uint32_t* fr = (const uint32_t*)(fn + (size_t)wid * DIM);
    const uint32_t* pr = (const uint32_t*)(fn + (size_t)partner * DIM);
    uint32_t a = fr[lane], p = pr[lane];
    float a0 = bf_lo(a), a1 = bf_hi(a);
    float p0 = bf_lo(p), p1 = bf_hi(p);
    float sd = a0 * a0 + a1 * a1;       // self dot  (diagonal recompute)
    float pd = a0 * p0 + a1 * p1;       // positive-pair dot
    #pragma unroll
    for (int m = 1; m < 64; m <<= 1) {
        sd += __shfl_xor(sd, m, 64);
        pd += __shfl_xor(pd, m, 64);
    }
    if (lane == 0) {
        float ep = E[wid] - fast_exp2(fmaf(sd, SCALE, -SCALE));   // drop diagonal
        sm[threadIdx.x >> 6] = INV_T + logf(ep) - pd * INV_T;
    }
    __syncthreads();
    if (threadIdx.x == 0)
        atomicAdd(out, (sm[0] + sm[1] + sm[2] + sm[3]) * (1.0f / N_ROWS));
}

extern "C" void kernel_launch(void* const* d_in, const int* in_sizes, int n_in,
                              void* d_out, int out_size, void* d_ws, size_t ws_size,
                              hipStream_t stream) {
    const float* feat = (const float*)d_in[0];
    float* out = (float*)d_out;

    // ws: fn (bf16, 2 MiB) | E (f32, 32 KiB)
    uint16_t* fn = (uint16_t*)d_ws;
    float* E     = (float*)((char*)d_ws + (size_t)N_ROWS * DIM * 2);

    hipMemsetAsync(E, 0, (size_t)N_ROWS * sizeof(float), stream);
    k_normalize<<<dim3(N_ROWS / 4), dim3(256), 0, stream>>>(feat, fn, out);
    k_simexp<<<dim3(NTRI), dim3(256), 0, stream>>>(fn, E);
    k_finalize<<<dim3(N_ROWS / 4), dim3(256), 0, stream>>>(fn, E, out);
}

// Round 7
// 45.929 us; speedup vs baseline: 2.0546x; 2.0546x over previous
//
#include <hip/hip_runtime.h>
#include <hip/hip_bf16.h>
#include <stdint.h>

// SimCLR loss, n=8192, d=128, T=0.07.
// R7: the R1-R6 invariant bottleneck was per-wave private B loads (divergent
// 16-line gathers, 4x redundant per block) saturating L1. Fix = m97-style
// LDS staging: 128-col chunks (32 KB) staged once per BLOCK via
// global_load_lds (XOR-swizzled source, linear dest; swizzled ds_read_b128),
// double-buffered, ONE barrier per chunk, stage(c+1) DMA overlapping
// compute(c). MFMA floor 8.3us.
//  k_normalize: fp32 -> row-L2-normalized bf16 fn
//  k_simexp:    E_part[row][slice] = sum_{j in slice} exp2((dot_ij-1)*s)
//  k_finalize:  per-row term; block partial -> terms[]
//  k_reduce:    mean -> out[0]

#define N_ROWS 8192
#define DIM    128
#define HALF_N 4096
#define N_SLICES 16
#define JCOLS (N_ROWS / N_SLICES)   // 512 cols per block
#define CHUNK 128                   // cols per staged chunk (32 KiB)
#define NCHUNK (JCOLS / CHUNK)      // 4
#define NJT (CHUNK / 16)            // 8 j-tiles per chunk

static constexpr float INV_T = 14.285714285714286f;   // 1/0.07
static constexpr float SCALE = 20.60992915555662f;    // log2(e)/0.07

typedef __attribute__((ext_vector_type(8))) short short8;   // 8 bf16 = 4 VGPR
typedef __attribute__((ext_vector_type(4))) float f32x4;

#if __has_builtin(__builtin_amdgcn_exp2f)
__device__ inline float fast_exp2(float x) { return __builtin_amdgcn_exp2f(x); }
#else
__device__ inline float fast_exp2(float x) { return exp2f(x); }
#endif

__device__ inline float bf_lo(uint32_t u) { return __uint_as_float(u << 16); }
__device__ inline float bf_hi(uint32_t u) { return __uint_as_float(u & 0xFFFF0000u); }
__device__ inline uint16_t f2bf(float x) {
    uint32_t u = __float_as_uint(x);
    return (uint16_t)((u + 0x7FFFu + ((u >> 16) & 1u)) >> 16);   // RNE
}

// async global->LDS, 16B/lane; LDS dest = wave-uniform base + lane*16 (HW)
__device__ inline void load_lds16(const void* g, void* l) {
    __builtin_amdgcn_global_load_lds(
        (const __attribute__((address_space(1))) uint32_t*)g,
        (__attribute__((address_space(3))) uint32_t*)l, 16, 0, 0);
}

// ---------------- kernel 1: row L2-normalize, fp32 -> bf16 ----------------
__global__ __launch_bounds__(256) void k_normalize(const float* __restrict__ f,
                                                   uint16_t* __restrict__ fn) {
    int wid  = (blockIdx.x * blockDim.x + threadIdx.x) >> 6;   // one wave per row
    int lane = threadIdx.x & 63;
    const float2* src = (const float2*)(f + (size_t)wid * DIM);
    float2 v = src[lane];
    float ss = v.x * v.x + v.y * v.y;
    #pragma unroll
    for (int m = 1; m < 64; m <<= 1) ss += __shfl_xor(ss, m, 64);
    float inv = rsqrtf(ss);
    ushort2 o;
    o.x = f2bf(v.x * inv);
    o.y = f2bf(v.y * inv);
    ((ushort2*)(fn + (size_t)wid * DIM))[lane] = o;
}

// ---------------- kernel 2: fused sim + exp-sum (MFMA, LDS-staged B) ------
// Grid (32, 16): block = 4 waves x 64 rows = 256 rows, 512 cols (one slice).
// LDS layout per chunk: col cc (0..127) at bytes cc*256 .. +255; 16B-slot pc
// holds logical k-chunk pc ^ (cc&7)  (bank-spread for stride-256B col reads).
__global__ __launch_bounds__(256) void k_simexp(const uint16_t* __restrict__ fn,
                                                float* __restrict__ E_part) {
    __shared__ __align__(16) uint16_t Bl[2][CHUNK * DIM];   // 2 x 32 KiB
    const int tid  = threadIdx.x;
    const int lane = tid & 63;
    const int w    = tid >> 6;
    const int ib   = blockIdx.x * 256 + w * 64;
    const int jc0  = blockIdx.y * JCOLS;
    const int lr = lane & 15;
    const int lk = lane >> 4;

    const short8* fn8 = (const short8*)fn;

    // A fragments (private): row ib+mt*16+lr, dims kc*32+lk*8..+8  (64 VGPR)
    short8 Af[4][4];
    #pragma unroll
    for (int mt = 0; mt < 4; ++mt)
        #pragma unroll
        for (int kc = 0; kc < 4; ++kc)
            Af[mt][kc] = fn8[(size_t)(ib + mt * 16 + lr) * 16 + kc * 4 + lk];

    float es[4][4];
    #pragma unroll
    for (int mt = 0; mt < 4; ++mt)
        #pragma unroll
        for (int r = 0; r < 4; ++r) es[mt][r] = 0.0f;

    // staging: wave w covers cols w*32..w*32+31 of the chunk; 8 instrs,
    // each 64 lanes x 16B = 4 cols. Lane l -> col cc, slot pc=l&15 holding
    // logical chunk lc = pc ^ (cc&7)  => fetch global chunk lc of col cc.
    const int scc0 = w * 32 + (lane >> 4);        // + i*4 per instr
    #define STAGE(c, buf)                                                     \
        _Pragma("unroll")                                                     \
        for (int i = 0; i < 8; ++i) {                                         \
            int cc = scc0 + i * 4;                                            \
            int lc = (lane & 15) ^ (cc & 7);                                  \
            load_lds16(fn8 + (size_t)(jc0 + (c) * CHUNK + cc) * 16 + lc,      \
                       &Bl[buf][w * 4096 + i * 512]);                         \
        }

    STAGE(0, 0)

    for (int c = 0; c < NCHUNK; ++c) {
        __syncthreads();                       // stage(c) drained & visible
        if (c + 1 < NCHUNK) {
            STAGE(c + 1, (c + 1) & 1)          // DMA overlaps compute(c)
        }
        const char* bp = (const char*)&Bl[c & 1][0];
        #pragma unroll
        for (int jt = 0; jt < NJT; ++jt) {
            // col = jt*16+lr; slot = (kc*4+lk) ^ (lr&7)
            const int rbase = (jt * 16 + lr) * 256;
            short8 Bf[4];
            #pragma unroll
            for (int kc = 0; kc < 4; ++kc)
                Bf[kc] = *(const short8*)(bp + rbase + ((((kc << 2) | lk) ^ (lr & 7)) << 4));
            #pragma unroll
            for (int mt = 0; mt < 4; ++mt) {
                f32x4 acc = {0.0f, 0.0f, 0.0f, 0.0f};
                #pragma unroll
                for (int kc = 0; kc < 4; ++kc)
                    acc = __builtin_amdgcn_mfma_f32_16x16x32_bf16(Af[mt][kc], Bf[kc], acc, 0, 0, 0);
                #pragma unroll
                for (int r = 0; r < 4; ++r)
                    es[mt][r] += fast_exp2(fmaf(acc[r], SCALE, -SCALE));
            }
        }
    }

    // C/D: col = lr, row = lk*4 + r. Reduce over 16 col-lanes; write rowsum.
    #pragma unroll
    for (int mt = 0; mt < 4; ++mt)
        #pragma unroll
        for (int r = 0; r < 4; ++r) {
            float v = es[mt][r];
            v += __shfl_xor(v, 1, 64);
            v += __shfl_xor(v, 2, 64);
            v += __shfl_xor(v, 4, 64);
            v += __shfl_xor(v, 8, 64);
            if (lr == 0)
                E_part[(size_t)(ib + mt * 16 + lk * 4 + r) * N_SLICES + blockIdx.y] = v;
        }
}

// ---------------- kernel 3: per-row finalize -> block partials ------------
__global__ __launch_bounds__(256) void k_finalize(const uint16_t* __restrict__ fn,
                                                  const float* __restrict__ E_part,
                                                  float* __restrict__ terms) {
    __shared__ float sm[4];
    int wid  = (blockIdx.x * blockDim.x + threadIdx.x) >> 6;   // one wave per row
    int lane = threadIdx.x & 63;
    int partner = (wid + HALF_N) & (N_ROWS - 1);
    const uint32_t* fr = (const uint32_t*)(fn + (size_t)wid * DIM);
    const uint32_t* pr = (const uint32_t*)(fn + (size_t)partner * DIM);
    uint32_t a = fr[lane], p = pr[lane];
    float a0 = bf_lo(a), a1 = bf_hi(a);
    float p0 = bf_lo(p), p1 = bf_hi(p);
    float sd = a0 * a0 + a1 * a1;       // self dot (diagonal recompute)
    float pd = a0 * p0 + a1 * p1;       // positive-pair dot
    #pragma unroll
    for (int m = 1; m < 64; m <<= 1) {
        sd += __shfl_xor(sd, m, 64);
        pd += __shfl_xor(pd, m, 64);
    }
    float e = (lane < N_SLICES) ? E_part[(size_t)wid * N_SLICES + lane] : 0.0f;
    #pragma unroll
    for (int m = 1; m < 64; m <<= 1) e += __shfl_xor(e, m, 64);
    if (lane == 0) {
        float ep = e - fast_exp2(fmaf(sd, SCALE, -SCALE));   // remove diagonal
        sm[threadIdx.x >> 6] = INV_T + logf(ep) - pd * INV_T;
    }
    __syncthreads();
    if (threadIdx.x == 0)
        terms[blockIdx.x] = sm[0] + sm[1] + sm[2] + sm[3];
}

// ---------------- kernel 4: mean over 2048 block partials ----------------
__global__ __launch_bounds__(256) void k_reduce(const float* __restrict__ terms,
                                                float* __restrict__ out) {
    __shared__ float sm[4];
    float acc = 0.0f;
    for (int i = threadIdx.x; i < N_ROWS / 4; i += 256) acc += terms[i];
    #pragma unroll
    for (int m = 1; m < 64; m <<= 1) acc += __shfl_xor(acc, m, 64);
    if ((threadIdx.x & 63) == 0) sm[threadIdx.x >> 6] = acc;
    __syncthreads();
    if (threadIdx.x == 0)
        out[0] = (sm[0] + sm[1] + sm[2] + sm[3]) * (1.0f / N_ROWS);
}

extern "C" void kernel_launch(void* const* d_in, const int* in_sizes, int n_in,
                              void* d_out, int out_size, void* d_ws, size_t ws_size,
                              hipStream_t stream) {
    const float* feat = (const float*)d_in[0];
    float* out = (float*)d_out;

    // ws: fn (bf16, 2 MiB) | E_part (f32, 8192*16*4 = 512 KiB) | terms (8 KiB)
    uint16_t* fn  = (uint16_t*)d_ws;
    float* E_part = (float*)((char*)d_ws + (size_t)N_ROWS * DIM * 2);
    float* terms  = E_part + (size_t)N_ROWS * N_SLICES;

    k_normalize<<<dim3(N_ROWS / 4), dim3(256), 0, stream>>>(feat, fn);
    k_simexp<<<dim3(N_ROWS / 256, N_SLICES), dim3(256), 0, stream>>>(fn, E_part);
    k_finalize<<<dim3(N_ROWS / 4), dim3(256), 0, stream>>>(fn, E_part, terms);
    k_reduce<<<dim3(1), dim3(256), 0, stream>>>(terms, out);
}